// Round 5
// baseline (1423.378 us; speedup 1.0000x reference)
//
#include <hip/hip_runtime.h>
#include <cstddef>
#include <cstdint>

// Problem constants
#define B_DIM   4
#define L_SEQ   2048
#define C_DIM   2048
#define OUT_DIM 768
#define NHEADS  32
#define HDIM    64
#define MBS_    16
#define NMINI   128
#define EPS_    1e-6f

typedef _Float16 half8 __attribute__((ext_vector_type(8)));
typedef _Float16 half4 __attribute__((ext_vector_type(4)));
typedef float floatx4 __attribute__((ext_vector_type(4)));

__device__ __forceinline__ void glds16(const void* g, void* l) {
    __builtin_amdgcn_global_load_lds(
        (const __attribute__((address_space(1))) uint32_t*)g,
        (__attribute__((address_space(3))) uint32_t*)l, 16, 0, 0);
}

__device__ __forceinline__ void split8(const float4 a, const float4 b,
                                       half8& hi, half8& lo) {
    const float x[8] = {a.x, a.y, a.z, a.w, b.x, b.y, b.z, b.w};
#pragma unroll
    for (int e = 0; e < 8; e++) {
        const _Float16 h = (_Float16)x[e];
        hi[e] = h;
        lo[e] = (_Float16)(x[e] - (float)h);
    }
}

__device__ __forceinline__ void split4(const float4 a, half4& hi, half4& lo) {
    const float x[4] = {a.x, a.y, a.z, a.w};
#pragma unroll
    for (int e = 0; e < 4; e++) {
        const _Float16 h = (_Float16)x[e];
        hi[e] = h;
        lo[e] = (_Float16)(x[e] - (float)h);
    }
}

// pack fp32 -> (hi fp16, lo fp16) in one dword (H low, L high)
__device__ __forceinline__ uint32_t pack_hl(float v) {
    const _Float16 h = (_Float16)v;
    const _Float16 l = (_Float16)(v - (float)h);
    union { _Float16 f[2]; uint32_t u; } p;
    p.f[0] = h; p.f[1] = l;
    return p.u;
}

// swap the (H,L) halves inside each dword of a half8 (rotate-16)
__device__ __forceinline__ half8 pairswap(half8 v) {
    union { half8 h; uint32_t u[4]; } a, b;
    a.h = v;
#pragma unroll
    for (int e = 0; e < 4; e++) b.u[e] = (a.u[e] >> 16) | (a.u[e] << 16);
    return b.h;
}

// DPP-based 16-lane (row) reduction: quad xor1, xor2, then row_ror 4, 8.
template<int CTRL>
__device__ __forceinline__ float dpp_add(float v) {
    const int x = __builtin_amdgcn_update_dpp(0, __float_as_int(v), CTRL, 0xF, 0xF, false);
    return v + __int_as_float(x);
}
__device__ __forceinline__ float red16(float v) {
    v = dpp_add<0xB1>(v);   // quad_perm(1,0,3,2) : xor 1
    v = dpp_add<0x4E>(v);   // quad_perm(2,3,0,1) : xor 2
    v = dpp_add<0x124>(v);  // row_ror:4
    v = dpp_add<0x128>(v);  // row_ror:8
    return v;
}

// barrier that drains ONLY LDS counters; vmem (prefetch loads / output
// stores) stay in flight across it.
__device__ __forceinline__ void bar_lgkm() {
    asm volatile("s_waitcnt lgkmcnt(0)\n\ts_barrier" ::: "memory");
}

// ======================================================================
// A pre-split: fp32 [M][K] -> fp16 hi/lo [M][K] (row-major, same order).
// ======================================================================
__global__ __launch_bounds__(256)
void asplit_kernel(const float* __restrict__ A, _Float16* __restrict__ Ahi,
                   _Float16* __restrict__ Alo)
{
    const size_t idx = ((size_t)blockIdx.x * 256 + threadIdx.x) * 16;
    half8 h0, l0, h1, l1;
    {
        const float4 a = *(const float4*)(A + idx);
        const float4 b = *(const float4*)(A + idx + 4);
        split8(a, b, h0, l0);
    }
    {
        const float4 a = *(const float4*)(A + idx + 8);
        const float4 b = *(const float4*)(A + idx + 12);
        split8(a, b, h1, l1);
    }
    *(half8*)(Ahi + idx)     = h0;
    *(half8*)(Ahi + idx + 8) = h1;
    *(half8*)(Alo + idx)     = l0;
    *(half8*)(Alo + idx + 8) = l1;
}

// ======================================================================
// Deep-pipelined MFMA GEMM v2: 256x128 tile, BK=32, triple-buffered LDS,
// counted vmcnt(6), and a FINE 4-sub-phase interleave per K-step:
// each phase {ds_read frag subtile; issue staging; lgkm-barrier; 12 MFMA}.
// Keeps waves phase-aligned so ds_read bursts and MFMA bursts from
// different waves interleave (m196/m201 mechanism). 512 thr = 8 waves.
// ======================================================================
__global__ __launch_bounds__(512)
void gemm8(const _Float16* __restrict__ Ahi, const _Float16* __restrict__ Alo,
           const _Float16* __restrict__ Bhi, const _Float16* __restrict__ Blo,
           float* __restrict__ Cout, int Ndim, int mode, int doRope)
{
    __shared__ __align__(16) _Float16 sAh[3][8192];  // [256][32]
    __shared__ __align__(16) _Float16 sAl[3][8192];
    __shared__ __align__(16) _Float16 sBh[3][4096];  // [128][32]
    __shared__ __align__(16) _Float16 sBl[3][4096];
    const int tid = threadIdx.x;
    const int nbx = Ndim >> 7;            // N / 128
    const int nwg = gridDim.x;            // multiple of 8
    int lin = blockIdx.x;
    lin = (lin & 7) * (nwg >> 3) + (lin >> 3);   // XCD swizzle (bijective)
    const int m0 = (lin / nbx) * 256;
    const int n0 = (lin % nbx) * 128;
    const int K = 2048;

    // staging addresses: LDS dest linear (chunk*16B), global src pre-swizzled
    size_t gA[2];
    int lA[2];
#pragma unroll
    for (int X = 0; X < 2; X++) {
        const int c = X * 512 + tid;
        const int row = c >> 2, s = c & 3;
        const int ks = s ^ ((row >> 1) & 3);
        gA[X] = (size_t)(m0 + row) * K + ks * 8;
        lA[X] = c * 8;
    }
    size_t gB;
    int lB;
    {
        const int row = tid >> 2, s = tid & 3;
        const int ks = s ^ ((row >> 1) & 3);
        gB = (size_t)(n0 + row) * K + ks * 8;
        lB = tid * 8;
    }

    const int lane = tid & 63, q = lane >> 4, lc = lane & 15;
    const int w = tid >> 6, wm = w >> 1, wn = w & 1;
    int offA[4], offB[4];
#pragma unroll
    for (int i = 0; i < 4; i++) {
        const int rA = wm * 64 + i * 16 + lc;
        offA[i] = rA * 32 + ((q ^ ((rA >> 1) & 3)) << 3);
    }
#pragma unroll
    for (int j = 0; j < 4; j++) {
        const int rB = wn * 64 + j * 16 + lc;
        offB[j] = rB * 32 + ((q ^ ((rB >> 1) & 3)) << 3);
    }

    floatx4 acc[4][4];
#pragma unroll
    for (int i = 0; i < 4; i++)
#pragma unroll
        for (int j = 0; j < 4; j++) acc[i][j] = (floatx4)0.0f;

#define STAGE_ALL(T)                                                     \
    {                                                                    \
        const int b_ = (T) % 3;                                          \
        const int ko_ = (T) * 32;                                        \
        glds16(Ahi + gA[0] + ko_, &sAh[b_][lA[0]]);                      \
        glds16(Alo + gA[0] + ko_, &sAl[b_][lA[0]]);                      \
        glds16(Ahi + gA[1] + ko_, &sAh[b_][lA[1]]);                      \
        glds16(Alo + gA[1] + ko_, &sAl[b_][lA[1]]);                      \
        glds16(Bhi + gB + ko_,    &sBh[b_][lB]);                         \
        glds16(Blo + gB + ko_,    &sBl[b_][lB]);                         \
    }

#define MFMA_I(i)                                                        \
    __builtin_amdgcn_s_setprio(1);                                       \
    _Pragma("unroll")                                                    \
    for (int j = 0; j < 4; j++) {                                        \
        acc[i][j] = __builtin_amdgcn_mfma_f32_16x16x32_f16(ah[i], bh[j], acc[i][j], 0, 0, 0); \
        acc[i][j] = __builtin_amdgcn_mfma_f32_16x16x32_f16(ah[i], bl[j], acc[i][j], 0, 0, 0); \
        acc[i][j] = __builtin_amdgcn_mfma_f32_16x16x32_f16(al[i], bh[j], acc[i][j], 0, 0, 0); \
    }                                                                    \
    __builtin_amdgcn_s_setprio(0);

    // prologue: stage tiles 0 and 1; publish tile 0
    STAGE_ALL(0)
    STAGE_ALL(1)
    asm volatile("s_waitcnt vmcnt(6) lgkmcnt(0)\n\ts_barrier" ::: "memory");

    // main loop: tiles 0..61; stage t+2 spread over phases; wait vmcnt(6)
    for (int t = 0; t < 62; t++) {
        const int b = t % 3;
        const int b2 = (t + 2) % 3;
        const int ko2 = (t + 2) * 32;
        half8 ah[4], al[4], bh[4], bl[4];
        // ---- phase 0: all B frags + A0; stage A-chunk0 ----
#pragma unroll
        for (int j = 0; j < 4; j++) {
            bh[j] = *(const half8*)&sBh[b][offB[j]];
            bl[j] = *(const half8*)&sBl[b][offB[j]];
        }
        ah[0] = *(const half8*)&sAh[b][offA[0]];
        al[0] = *(const half8*)&sAl[b][offA[0]];
        glds16(Ahi + gA[0] + ko2, &sAh[b2][lA[0]]);
        glds16(Alo + gA[0] + ko2, &sAl[b2][lA[0]]);
        bar_lgkm();
        MFMA_I(0)
        // ---- phase 1: A1; stage A-chunk1 ----
        ah[1] = *(const half8*)&sAh[b][offA[1]];
        al[1] = *(const half8*)&sAl[b][offA[1]];
        glds16(Ahi + gA[1] + ko2, &sAh[b2][lA[1]]);
        glds16(Alo + gA[1] + ko2, &sAl[b2][lA[1]]);
        bar_lgkm();
        MFMA_I(1)
        // ---- phase 2: A2; stage B ----
        ah[2] = *(const half8*)&sAh[b][offA[2]];
        al[2] = *(const half8*)&sAl[b][offA[2]];
        glds16(Bhi + gB + ko2, &sBh[b2][lB]);
        glds16(Blo + gB + ko2, &sBl[b2][lB]);
        bar_lgkm();
        MFMA_I(2)
        // ---- phase 3: A3; counted-vmcnt publish of tile t+1 ----
        ah[3] = *(const half8*)&sAh[b][offA[3]];
        al[3] = *(const half8*)&sAl[b][offA[3]];
        asm volatile("s_waitcnt vmcnt(6) lgkmcnt(0)\n\ts_barrier" ::: "memory");
        MFMA_I(3)
    }
    // tile 62: no staging left; drain all, publish tile 63
    {
        half8 ah[4], al[4], bh[4], bl[4];
#pragma unroll
        for (int j = 0; j < 4; j++) {
            bh[j] = *(const half8*)&sBh[2][offB[j]];
            bl[j] = *(const half8*)&sBl[2][offB[j]];
        }
#pragma unroll
        for (int i = 0; i < 4; i++) {
            ah[i] = *(const half8*)&sAh[2][offA[i]];
            al[i] = *(const half8*)&sAl[2][offA[i]];
        }
        asm volatile("s_waitcnt vmcnt(0) lgkmcnt(0)" ::: "memory");
        MFMA_I(0) MFMA_I(1) MFMA_I(2) MFMA_I(3)
        __syncthreads();
    }
    // tile 63: compute only
    {
        half8 ah[4], al[4], bh[4], bl[4];
#pragma unroll
        for (int j = 0; j < 4; j++) {
            bh[j] = *(const half8*)&sBh[0][offB[j]];
            bl[j] = *(const half8*)&sBl[0][offB[j]];
        }
#pragma unroll
        for (int i = 0; i < 4; i++) {
            ah[i] = *(const half8*)&sAh[0][offA[i]];
            al[i] = *(const half8*)&sAl[0][offA[i]];
        }
        MFMA_I(0) MFMA_I(1) MFMA_I(2) MFMA_I(3)
    }
#undef STAGE_ALL
#undef MFMA_I

    float cs[4][4], sn[4][4];
    if (doRope) {
#pragma unroll
        for (int j = 0; j < 4; j++) {
            const int ii = ((j * 16 + lc) & 63) >> 1;
            const float invf = expf(-(float)ii * 0.28782313662425574f);
#pragma unroll
            for (int r = 0; r < 4; r++) {
                const float ang = (float)(q * 4 + r) * invf;
                sincosf(ang, &sn[j][r], &cs[j][r]);
            }
        }
    }
    const int oddcol = lc & 1;
#pragma unroll
    for (int i = 0; i < 4; i++) {
#pragma unroll
        for (int j = 0; j < 4; j++) {
            floatx4 v = acc[i][j];
            if (doRope) {
#pragma unroll
                for (int r = 0; r < 4; r++) {
                    const float partner = __shfl_xor(v[r], 1);
                    v[r] = v[r] * cs[j][r] + partner * (oddcol ? sn[j][r] : -sn[j][r]);
                }
            }
            const int n = n0 + wn * 64 + j * 16 + lc;
            if (mode == 0) {
                const int h = (n >> 6) & 31, d = n & 63;
#pragma unroll
                for (int r = 0; r < 4; r++) {
                    const int m = m0 + wm * 64 + i * 16 + q * 4 + r;
                    const int b = m >> 11, li = m & 2047;
                    Cout[((size_t)(b * 32 + h) * 2048 + li) * 64 + d] = v[r];
                }
            } else {
#pragma unroll
                for (int r = 0; r < 4; r++) {
                    const int m = m0 + wm * 64 + i * 16 + q * 4 + r;
                    Cout[(size_t)m * OUT_DIM + n] = v[r];
                }
            }
        }
    }
}

// ======================================================================
// Fallback MFMA GEMM (fp32 A split on the fly) — only used if workspace
// is too small for the pre-split path. 128x128 tile, 256 threads.
// ======================================================================
__global__ __launch_bounds__(256)
void gemm_f32(const float* __restrict__ A,
              const _Float16* __restrict__ Bhi, const _Float16* __restrict__ Blo,
              float* __restrict__ Cout, int mode, int doRope)
{
    __shared__ __align__(16) float    sA[4096];
    __shared__ __align__(16) _Float16 sBhi[4096];
    __shared__ __align__(16) _Float16 sBlo[4096];
    const int tid = threadIdx.x;
    const int m0 = blockIdx.y * 128, n0 = blockIdx.x * 128;
    const int K = 2048;

    size_t gA[4]; float* lA[4];
#pragma unroll
    for (int I = 0; I < 4; I++) {
        const int c = I * 256 + tid;
        const int row = c >> 3, seg = (c & 7) ^ (row & 7);
        gA[I] = (size_t)(m0 + row) * K + seg * 4;
        lA[I] = &sA[c * 4];
    }
    size_t gB[2]; _Float16 *lBh[2], *lBl[2];
#pragma unroll
    for (int I = 0; I < 2; I++) {
        const int c = I * 256 + tid;
        const int row = c >> 2, seg = (c & 3) ^ ((row >> 1) & 3);
        gB[I] = (size_t)(n0 + row) * K + seg * 8;
        lBh[I] = &sBhi[c * 8];
        lBl[I] = &sBlo[c * 8];
    }

    const int lane = tid & 63, quad = lane >> 4, lc = lane & 15;
    const int wv = tid >> 6, wm = wv & 1, wn = wv >> 1;
    int offA0[4], offA1[4], offB[4];
#pragma unroll
    for (int i = 0; i < 4; i++) {
        const int rA = wm * 64 + i * 16 + lc;
        offA0[i] = (rA * 8 + ((2 * quad)     ^ (rA & 7))) * 4;
        offA1[i] = (rA * 8 + ((2 * quad + 1) ^ (rA & 7))) * 4;
    }
#pragma unroll
    for (int j = 0; j < 4; j++) {
        const int rB = wn * 64 + j * 16 + lc;
        offB[j] = (rB * 4 + (quad ^ ((rB >> 1) & 3))) * 8;
    }

    floatx4 acc[4][4];
#pragma unroll
    for (int i = 0; i < 4; i++)
#pragma unroll
        for (int j = 0; j < 4; j++) acc[i][j] = (floatx4)0.0f;

    for (int k0 = 0; k0 < K; k0 += 32) {
        __syncthreads();
#pragma unroll
        for (int I = 0; I < 4; I++) glds16(A + gA[I] + k0, lA[I]);
#pragma unroll
        for (int I = 0; I < 2; I++) {
            glds16(Bhi + gB[I] + k0, lBh[I]);
            glds16(Blo + gB[I] + k0, lBl[I]);
        }
        __syncthreads();

        half8 ah[4], al[4], bh[4], bl[4];
#pragma unroll
        for (int i = 0; i < 4; i++) {
            const float4 va = *(const float4*)&sA[offA0[i]];
            const float4 vb = *(const float4*)&sA[offA1[i]];
            split8(va, vb, ah[i], al[i]);
        }
#pragma unroll
        for (int j = 0; j < 4; j++) {
            bh[j] = *(const half8*)&sBhi[offB[j]];
            bl[j] = *(const half8*)&sBlo[offB[j]];
        }
#pragma unroll
        for (int i = 0; i < 4; i++)
#pragma unroll
            for (int j = 0; j < 4; j++) {
                acc[i][j] = __builtin_amdgcn_mfma_f32_16x16x32_f16(ah[i], bh[j], acc[i][j], 0, 0, 0);
                acc[i][j] = __builtin_amdgcn_mfma_f32_16x16x32_f16(ah[i], bl[j], acc[i][j], 0, 0, 0);
                acc[i][j] = __builtin_amdgcn_mfma_f32_16x16x32_f16(al[i], bh[j], acc[i][j], 0, 0, 0);
            }
    }

    float cs[4][4], sn[4][4];
    if (doRope) {
#pragma unroll
        for (int j = 0; j < 4; j++) {
            const int ii = ((j * 16 + lc) & 63) >> 1;
            const float invf = expf(-(float)ii * 0.28782313662425574f);
#pragma unroll
            for (int r = 0; r < 4; r++) {
                const float ang = (float)(quad * 4 + r) * invf;
                sincosf(ang, &sn[j][r], &cs[j][r]);
            }
        }
    }
    const int oddcol = lc & 1;
#pragma unroll
    for (int i = 0; i < 4; i++) {
#pragma unroll
        for (int j = 0; j < 4; j++) {
            floatx4 v = acc[i][j];
            if (doRope) {
#pragma unroll
                for (int r = 0; r < 4; r++) {
                    const float partner = __shfl_xor(v[r], 1);
                    v[r] = v[r] * cs[j][r] + partner * (oddcol ? sn[j][r] : -sn[j][r]);
                }
            }
            const int n = n0 + wn * 64 + j * 16 + lc;
            if (mode == 0) {
                const int h = (n >> 6) & 31, d = n & 63;
#pragma unroll
                for (int r = 0; r < 4; r++) {
                    const int m = m0 + wm * 64 + i * 16 + quad * 4 + r;
                    const int b = m >> 11, li = m & 2047;
                    Cout[((size_t)(b * 32 + h) * 2048 + li) * 64 + d] = v[r];
                }
            } else {
#pragma unroll
                for (int r = 0; r < 4; r++) {
                    const int m = m0 + wm * 64 + i * 16 + quad * 4 + r;
                    Cout[(size_t)m * OUT_DIM + n] = v[r];
                }
            }
        }
    }
}

// ======================================================================
// Weight transpose + split (unchanged)
// ======================================================================
__global__ __launch_bounds__(256)
void wtrans_kernel(const float* __restrict__ W, _Float16* __restrict__ BThi,
                   _Float16* __restrict__ BTlo, int Nw)
{
    __shared__ float tile[32][33];
    const int t = threadIdx.x, tx = t & 31, ty = t >> 5;
    const int n0 = blockIdx.x * 32, k0 = blockIdx.y * 32;
    const int K = 2048;
#pragma unroll
    for (int r = 0; r < 4; r++)
        tile[ty + r * 8][tx] = W[(size_t)(k0 + ty + r * 8) * Nw + n0 + tx];
    __syncthreads();
#pragma unroll
    for (int r = 0; r < 4; r++) {
        const float val = tile[tx][ty + r * 8];
        const _Float16 hh = (_Float16)val;
        const size_t o = (size_t)(n0 + ty + r * 8) * K + k0 + tx;
        BThi[o] = hh;
        BTlo[o] = (_Float16)(val - (float)hh);
    }
}

// ======================================================================
// ttt_lr sigmoid (unchanged)
// ======================================================================
__global__ __launch_bounds__(256)
void lr_kernel(const float* __restrict__ hidden, const float* __restrict__ wlr,
               const float* __restrict__ lr_bias, float* __restrict__ lrs)
{
    __shared__ float sRow[2048];
    __shared__ float sPart[32][9];
    const int m = blockIdx.x;
    const int t = threadIdx.x;
    const float* row = hidden + (size_t)m * C_DIM;
#pragma unroll
    for (int j = 0; j < 8; j++) sRow[t + j * 256] = row[t + j * 256];
    __syncthreads();
    const int h = t >> 3, p = t & 7;
    const float* w = wlr + (size_t)h * C_DIM;
    float s = 0.0f;
#pragma unroll 8
    for (int k = 0; k < 64; k++) {
        const int c = k * 32 + p * 4;
        const float4 a = *(const float4*)(sRow + c);
        const float4 b = *(const float4*)(w + c);
        s += a.x * b.x + a.y * b.y + a.z * b.z + a.w * b.w;
    }
    sPart[h][p] = s;
    __syncthreads();
    if (t < 32) {
        float v = 0.0f;
#pragma unroll
        for (int p2 = 0; p2 < 8; p2++) v += sPart[t][p2];
        v += lr_bias[t];
        const float sig = 1.0f / (1.0f + expf(-v));
        lrs[((size_t)(m >> 11) * NHEADS + t) * L_SEQ + (m & 2047)] = sig;
    }
}

// ======================================================================
// MFMA TTT scan v4: TWO lgkm-only barriers/step (was 3).
//  - barrier F deleted: out-store for step n deferred to after barrier A
//    of step n+1 (sRedC write(n) post-barB(n) / read post-barA(n+1);
//    write(n+1) post-barB(n+1) -> single-buffered is safe).
//  - sKT double-buffered (reader(n) post-barB(n) vs writer(n+2) at
//    stage(n+2) have no intervening barrier on the same buffer parity
//    otherwise).
//  - z1a/zba/at accumulation chains split 6 -> 3+3.
//  - W1 writeback / b1 update are intra-wave (each wave owns its rows).
// ======================================================================
__global__ __launch_bounds__(256, 1)
void scan_mfma(const float* __restrict__ XQ, const float* __restrict__ XK,
               float* __restrict__ XVo, const float* __restrict__ LRS,
               const float* __restrict__ W1i, const float* __restrict__ b1i,
               const float* __restrict__ lt, const float* __restrict__ lnw,
               const float* __restrict__ lnb)
{
    __shared__ __align__(16) _Float16 sXqH[1024], sXqL[1024];   // [16][64] hi/lo
    __shared__ __align__(16) _Float16 sXkH[1024], sXkL[1024];   // [16][64] hi/lo
    __shared__ __align__(16) float    sTgt[16 * 68];            // xv - xk, plain
    __shared__ __align__(16) float    sXq32[2][16 * 68];        // fp32 xq, dbuf
    __shared__ __align__(16) _Float16 sW1H[4096], sW1L[4096];   // [64 n][64 k]
    __shared__ __align__(16) uint32_t sKT[2][64 * 20];          // packed XkT, dbuf
    __shared__ __align__(16) uint32_t sCf[16 * 20];             // packed coeff
    __shared__ __align__(16) float sRedA[16 * 36];              // 6 sums x 4 waves
    __shared__ __align__(16) float sRedC[16 * 12];              // 2 sums x 4 waves
    __shared__ __align__(16) float sEta[16];
    __shared__ float sB1[64];

    const int bh = blockIdx.x, h = bh & 31;
    const int t = threadIdx.x;
    const int lane = t & 63, q = lane >> 4, lc = lane & 15;
    const int w = t >> 6;
    const int col = w * 16 + lc;     // this lane's output column n
    const int iRow = t >> 4;         // staging row (0..15)
    const int m = t & 15;            // staging col group

    if (t < 64) sB1[t] = b1i[h * 64 + t];

    // W1 state regs: w1s[t4][r] = W1T[16w+4q+r][16t4+lc]
    float w1s[4][4];
#pragma unroll
    for (int t4 = 0; t4 < 4; t4++)
#pragma unroll
        for (int r = 0; r < 4; r++) {
            const float v = W1i[h * 4096 + (16 * t4 + lc) * 64 + (16 * w + 4 * q + r)];
            w1s[t4][r] = v;
            const int nn = 16 * w + 4 * q + r, k = 16 * t4 + lc;
            const int off = nn * 64 + ((((k >> 3) ^ (nn & 7)) << 3) | (k & 7));
            const _Float16 hh = (_Float16)v;
            sW1H[off] = hh; sW1L[off] = (_Float16)(v - (float)hh);
        }

    const float gamC = lnw[h * 64 + col], betC = lnb[h * 64 + col];
    const float g2c = gamC * gamC;
    // sum of gamma^2 over the 64 cols (constant for all rows/steps)
    float sumG2 = 0.0f;
#pragma unroll
    for (int d0 = 0; d0 < 16; d0++) {
        const float4 gv = *(const float4*)(lnw + h * 64 + d0 * 4);
        sumG2 += gv.x * gv.x + gv.y * gv.y + gv.z * gv.z + gv.w * gv.w;
    }
    float tokR[4];
#pragma unroll
    for (int r = 0; r < 4; r++)
        tokR[r] = fmaxf(1.0f / (float)(4 * q + r + 1) + lt[4 * q + r], 0.0f);
    const float tok15 = fmaxf(1.0f / 16.0f + lt[15], 0.0f);

    __syncthreads();

    const size_t base = (size_t)bh * L_SEQ * HDIM;
    const float* xq_g = XQ + base;
    const float* xk_g = XK + base;
    float* xv_g = XVo + base;
    const float* lr_g = LRS + (size_t)bh * L_SEQ;

    // preload minibatch 0 (thread t: row t>>4, cols 4m..4m+3)
    float4 cq = *(const float4*)(xq_g + t * 4);
    float4 ck = *(const float4*)(xk_g + t * 4);
    float4 cv = *(const float4*)(xv_g + t * 4);
    float clr = lr_g[m];

    const int rw = 16 * w + lc;
    // per-thread staging constants
    const int stOff = iRow * 64 + ((((m >> 1) ^ (iRow & 7)) << 3) | ((m & 1) << 2));
    const int gkm = (m ^ (m >> 2)) & 3;
    const int ktWb = 4 * (w ^ gkm) + q;          // sKT write col base (j = iRow)

    float z2p[4] = {0.0f, 0.0f, 0.0f, 0.0f};     // carried Zbar(n-1)+b1

    for (int n = 0; n < NMINI; n++) {
        const int buf = n & 1;
        // prefetch next minibatch FIRST (stays in flight across barriers)
        const int np = (n + 1) & (NMINI - 1);
        const float4 nq = *(const float4*)(xq_g + np * 1024 + t * 4);
        const float4 nk = *(const float4*)(xk_g + np * 1024 + t * 4);
        const float4 nv = *(const float4*)(xv_g + np * 1024 + t * 4);
        const float nlr = lr_g[np * 16 + m];
        // ---- stage current minibatch ----
        {
            half4 hq, lq, hk, lk;
            split4(cq, hq, lq);
            split4(ck, hk, lk);
            *(half4*)&sXqH[stOff] = hq;
            *(half4*)&sXqL[stOff] = lq;
            *(half4*)&sXkH[stOff] = hk;
            *(half4*)&sXkL[stOff] = lk;
            const float4 tg = make_float4(cv.x - ck.x, cv.y - ck.y,
                                          cv.z - ck.z, cv.w - ck.w);
            *(float4*)&sTgt[iRow * 68 + m * 4] = tg;
            *(float4*)&sXq32[buf][iRow * 68 + m * 4] = cq;
            const float kvv[4] = {ck.x, ck.y, ck.z, ck.w};
#pragma unroll
            for (int i2 = 0; i2 < 4; i2++)
                sKT[buf][(4 * m + i2) * 20 + ktWb] = pack_hl(kvv[i2]);
        }
        if (t < 16) sEta[t] = clr * (1.0f / 64.0f);
        bar_lgkm();   // A

        // ---- deferred out-store for step n-1 ----
        if (n) {
            const int pb = buf ^ 1;
#pragma unroll
            for (int r = 0; r < 4; r++) {
                const int row = 4 * q + r;
                const float4 a = *(const float4*)&sRedC[row * 12];
                const float4 b = *(const float4*)&sRedC[row * 12 + 4];
                const float mu  = (a.x + a.y + a.z + a.w) * (1.0f / 64.0f);
                const float ex2 = (b.x + b.y + b.z + b.w) * (1.0f / 64.0f);
                const float rs  = rsqrtf(ex2 - mu * mu + EPS_);
                const float xqv = sXq32[pb][row * 68 + col];
                xv_g[(n - 1) * 1024 + row * 64 + col] =
                    xqv + gamC * ((z2p[r] - mu) * rs) + betC;
            }
        }

        const float b1c = sB1[col];
        const float4 ev = *(const float4*)&sEta[4 * q];
        const float evv[4] = {ev.x, ev.y, ev.z, ev.w};

        // ---- forward fragments ----
        half8 qh[2], ql[2], kh[2], kl[2], wh[2], wl[2];
#pragma unroll
        for (int f = 0; f < 2; f++) {
            const int cx = ((4 * f + q) ^ (lc & 7)) << 3;
            qh[f] = *(const half8*)&sXqH[lc * 64 + cx];
            ql[f] = *(const half8*)&sXqL[lc * 64 + cx];
            kh[f] = *(const half8*)&sXkH[lc * 64 + cx];
            kl[f] = *(const half8*)&sXkL[lc * 64 + cx];
            const int cw = ((4 * f + q) ^ (rw & 7)) << 3;
            wh[f] = *(const half8*)&sW1H[rw * 64 + cw];
            wl[f] = *(const half8*)&sW1L[rw * 64 + cw];
        }

        // ---- forward MFMAs (split chains: f=0 / f=1 accumulate apart) ----
        floatx4 z1a = (floatx4)0.0f, z1b = (floatx4)0.0f;
        floatx4 zb0 = (floatx4)0.0f, zb1 = (floatx4)0.0f;
        z1a = __builtin_amdgcn_mfma_f32_16x16x32_f16(kh[0], wh[0], z1a, 0, 0, 0);
        z1a = __builtin_amdgcn_mfma_f32_16x16x32_f16(kh[0], wl[0], z1a, 0, 0, 0);
        z1a = __builtin_amdgcn_mfma_f32_16x16x32_f16(kl[0], wh[0], z1a, 0, 0, 0);
        z1b = __builtin_amdgcn_mfma_f32_16x16x32_f16(kh[1], wh[1], z1b, 0, 0, 0);
        z1b = __builtin_amdgcn_mfma_f32_16x16x32_f16(kh[1], wl[1], z1b, 0, 0, 0);
        z1b = __builtin_amdgcn_mfma_f32_16x16x32_f16(kl[1], wh[1], z1b, 0, 0, 0);
        zb0 = __builtin_amdgcn_mfma_f32_16x16x32_f16(qh[0], wh[0], zb0, 0, 0, 0);
        zb0 = __builtin_amdgcn_mfma_f32_16x16x32_f16(qh[0], wl[0], zb0, 0, 0, 0);
        zb0 = __builtin_amdgcn_mfma_f32_16x16x32_f16(ql[0], wh[0], zb0, 0, 0, 0);
        zb1 = __builtin_amdgcn_mfma_f32_16x16x32_f16(qh[1], wh[1], zb1, 0, 0, 0);
        zb1 = __builtin_amdgcn_mfma_f32_16x16x32_f16(qh[1], wl[1], zb1, 0, 0, 0);
        zb1 = __builtin_amdgcn_mfma_f32_16x16x32_f16(ql[1], wh[1], zb1, 0, 0, 0);
        // wave 0: Attn + packed coeff (read after barrier B)
        if (w == 0) {
            const float etaLC = sEta[lc];
            floatx4 at0 = (floatx4)0.0f, at1 = (floatx4)0.0f;
            at0 = __builtin_amdgcn_mfma_f32_16x16x32_f16(qh[0], kh[0], at0, 0, 0, 0);
            at0 = __builtin_amdgcn_mfma_f32_16x16x32_f16(qh[0], kl[0], at0, 0, 0, 0);
            at0 = __builtin_amdgcn_mfma_f32_16x16x32_f16(ql[0], kh[0], at0, 0, 0, 0);
            at1 = __builtin_amdgcn_mfma_f32_16x16x32_f16(qh[1], kh[1], at1, 0, 0, 0);
            at1 = __builtin_amdgcn_mfma_f32_16x16x32_f16(qh[1], kl[1], at1, 0, 0, 0);
            at1 = __builtin_amdgcn_mfma_f32_16x16x32_f16(ql[1], kh[1], at1, 0, 0, 0);
#pragma unroll
            for (int r = 0; r < 4; r++) {
                const int i = 4 * q + r;
                const float atv = at0[r] + at1[r];
                const float cfv = (lc <= i) ? -tokR[r] * etaLC * (atv + 1.0f) : 0.0f;
                sCf[i * 20 + 4 * ((lc >> 2) ^ q) + (lc & 3)] = pack_hl(cfv);
            }
        }

        // ---- merged Z1 + grad stats: 6 sums, one barrier ----
        float z[4], cE[4];
        float sz[4], szz[4], sgz[4], sgzz[4], sc[4], scz[4];
#pragma unroll
        for (int r = 0; r < 4; r++) {
            const int row = 4 * q + r;
            z[r] = z1a[r] + z1b[r] + b1c;
            const float tgt = sTgt[row * 68 + col];
            cE[r] = gamC * (betC - tgt);
            const float zz = z[r] * z[r];
            sz[r]   = red16(z[r]);
            szz[r]  = red16(zz);
            sgz[r]  = red16(g2c * z[r]);
            sgzz[r] = red16(g2c * zz);
            sc[r]   = red16(cE[r]);
            scz[r]  = red16(cE[r] * z[r]);
        }
        if (lc == 0) {
#pragma unroll
            for (int r = 0; r < 4; r++) {
                const int rb = (4 * q + r) * 36;
                sRedA[rb + 0  + w] = sz[r];
                sRedA[rb + 4  + w] = szz[r];
                sRedA[rb + 8  + w] = sgz[r];
                sRedA[rb + 12 + w] = sgzz[r];
                sRedA[rb + 16 + w] = sc[r];
                sRedA[rb + 20 + w] = scz[r];
            }
        }
        bar_lgkm();   // B

        // operand loads (cross-wave data, ordered by B)
        half8 ktp[4];
#pragma unroll
        for (int t4 = 0; t4 < 4; t4++) {
            const int gkr = ((lc >> 2) ^ t4) & 3;
            ktp[t4] = *(const half8*)&sKT[buf][(16 * t4 + lc) * 20 + 4 * (q ^ gkr)];
        }
        const half8 cfp = *(const half8*)&sCf[lc * 20 + 4 * (q ^ (lc >> 2))];

        // finish stats, closed-form G1/G2, grad
        float gr[4];
#pragma unroll
        for (int r = 0; r < 4; r++) {
            const int rb = (4 * q + r) * 36;
            const float4 a0 = *(const float4*)&sRedA[rb + 0];
            const float4 a1 = *(const float4*)&sRedA[rb + 4];
            const float4 a2 = *(const float4*)&sRedA[rb + 8];
            const float4 a3 = *(const float4*)&sRedA[rb + 12];
            const float4 a4 = *(const float4*)&sRedA[rb + 16];
            const float4 a5 = *(const float4*)&sRedA[rb + 20];
            const float Sz   = a0.x + a0.y + a0.z + a0.w;
            const float Szz  = a1.x + a1.y + a1.z + a1.w;
            const float Sgz  = a2.x + a2.y + a2.z + a2.w;
            const float Sgzz = a3.x + a3.y + a3.z + a3.w;
            const float Sc   = a4.x + a4.y + a4.z + a4.w;
            const float Scz  = a5.x + a5.y + a5.z + a5.w;
            const float mu  = Sz * (1.0f / 64.0f);
            const float ex2 = Szz * (1.0f / 64.0f);
            const float rs  = rsqrtf(ex2 - mu * mu + EPS_);
            const float G1 = rs * (Sgz - mu * sumG2) + Sc;
            const float G2 = rs * rs * (Sgzz - 2.0f * mu * Sgz + mu * mu * sumG2)
                           + rs * (Scz - mu * Sc);
            const float xh = (z[r] - mu) * rs;
            const float g  = g2c * xh + cE[r];
            gr[r] = (64.0f * g - G1 - xh * G2) * rs * (1.0f / 64.0f);
        }

        // lane-local packed grad fragments (plain + eta-scaled)
        half8 gf, gfl;
#pragma unroll
        for (int r = 0; r < 4; r++) {
            const _Float16 h0 = (_Float16)gr[r];
            gf[2 * r]     = h0;
            gf[2 * r + 1] = (_Float16)(gr[r] - (float)h0);
            const float gl = gr[r] * (tok15 * evv[r]);
            const _Float16 h1 = (_Float16)gl;
            gfl[2 * r]     = h1;
            gfl[2 * r + 1] = (_Float16)(gl - (float)h1);
        }
        const half8 gfs  = pairswap(gf);
        const half8 gfls = pairswap(gfl);

        // Zbar -= coeff @ grad   (full product in 2 MFMAs)
        floatx4 zba;
#pragma unroll
        for (int r = 0; r < 4; r++) zba[r] = zb0[r] + zb1[r];
        zba = __builtin_amdgcn_mfma_f32_16x16x32_f16(cfp, gf,  zba, 0, 0, 0);
        zba = __builtin_amdgcn_mfma_f32_16x16x32_f16(cfp, gfs, zba, 0, 0, 0);
        // W1 -= (eta*grad)^T @ XkT  (2 MFMAs per 16-col block)
#pragma unroll
        for (int t4 = 0; t4 < 4; t4++) {
            floatx4 up = (floatx4)0.0f;
            up = __builtin_amdgcn_mfma_f32_16x16x32_f16(gfl,  ktp[t4], up, 0, 0, 0);
            up = __builtin_amdgcn_mfma_f32_16x16x32_f16(gfls, ktp[t4], up, 0, 0, 0);
#pragma unroll
            for (int r = 0; r < 4; r++) w1s[t4][r] -= up[r];
        }

        // ---- Zbar stats (partials written; read after NEXT barrier A) ----
        float z2[4], p1[4], p2[4];
#pragma unroll
        for (int r = 0; r < 4; r++) {
            z2[r] = zba[r] + b1c;
            p1[r] = red16(z2[r]);
            p2[r] = red16(z2[r] * z2[r]);
        }
        if (lc == 0)
#pragma unroll
            for (int r = 0; r < 4; r++) {
                const int rb = (4 * q + r) * 12;
                sRedC[rb + w]     = p1[r];
                sRedC[rb + 4 + w] = p2[r];
            }

        // ---- b1 update (intra-wave) ----
        {
            float p = gr[0] * evv[0] + gr[1] * evv[1] + gr[2] * evv[2] + gr[3] * evv[3];
            p += __shfl_xor(p, 16);
            p += __shfl_xor(p, 32);
            if (q == 0) sB1[col] -= tok15 * p;
        }
        // ---- W1 regs -> LDS (intra-wave; own rows only) ----
#pragma unroll
        for (int t4 = 0; t4 < 4; t4++)
#pragma unroll
            for (int r = 0; r < 4; r++) {
                const int nn = 16 * w + 4 * q + r, k = 16 * t4 + lc;
                const int off = nn * 64 + ((((k >> 3) ^ (nn & 7)) << 3) | (k & 7));
                const float v = w1s[t4][r];
                const _Float16 hh = (_Float16)v;
                sW1H[off] = hh; sW1L[off] = (_Float16)(v - (float)hh);
            }

#pragma unroll
        for (int r = 0; r < 4; r++) z2p[r] = z2[r];
        cq = nq; ck = nk; cv = nv; clr = nlr;
    }

    // ---- epilogue: out-store for the last step (n = 127, buf = 1) ----
    bar_lgkm();
#pragma unroll
    for (int r = 0; r < 4; r++) {
        const int row = 4 * q + r;
        const float4 a = *(const float4*)&sRedC[row * 12];
        const float4 b = *(const float4*)&sRedC[row * 12 + 4];
        const float mu  = (a.x + a.y + a.z + a.w) * (1.0f / 64.0f);
        const float ex2 = (b.x + b.y + b.z + b.w) * (1.0f / 64.0f);
        const float rs  = rsqrtf(ex2 - mu * mu + EPS_);
        const float xqv = sXq32[1][row * 68 + col];
        xv_g[(NMINI - 1) * 1024 + row * 64 + col] =
            xqv + gamC * ((z2p[r] - mu) * rs) + betC;
    }
}

// ======================================================================
// post-norm: gather (B,NH,L,HD) -> LN over C=2048 -> fp16 hi/lo (B,L,C)
// (writes the pre-split A operand of the final GEMM directly)
// ======================================================================
__global__ __launch_bounds__(256)
void postln_kernel(const float* __restrict__ Ob, const float* __restrict__ pnw,
                   const float* __restrict__ pnb, _Float16* __restrict__ XNhi,
                   _Float16* __restrict__ XNlo)
{
    const int m = blockIdx.x;
    const int b = m >> 11, l = m & 2047;
    const int t = threadIdx.x;
    float v[8];
    float s1 = 0.0f, s2 = 0.0f;
    const int c0 = t * 8;
    const int hh = c0 >> 6, d0 = c0 & 63;
    const float* bas = Ob + (size_t)b * NHEADS * L_SEQ * HDIM + (size_t)l * HDIM
                     + (size_t)hh * (L_SEQ * HDIM) + d0;
    {
        const float4 va = *(const float4*)(bas);
        const float4 vb = *(const float4*)(bas + 4);
        v[0] = va.x; v[1] = va.y; v[2] = va.z; v[3] = va.w;
        v[4] = vb.x; v[5] = vb.y; v[6] = vb.z; v[7] = vb.w;
    }
#pragma unroll
    for (int j = 0; j < 8; j++) { s1 += v[j]; s2 += v[j] * v[j]; }
#pragma unroll
    for (int o = 1; o < 64; o <<= 1) { s1 += __shfl_xor(s1, o); s2 += __shfl_xor(s2, o); }
    __shared__ float r1[4], r2[4];
    const int w = t >> 6;
    if ((t & 63) == 0) { r1[w] = s1; r2[w] = s2; }
    __syncthreads();
    s1 = r1[0] + r1[1] + r1[2] + r1[3];
    s2 = r2[0] + r2[1] + r2[2] + r2[3];
    const float mu = s1 * (1.0f / 2048.0f);
    const float var = s2 * (1.0f / 2048.0f) - mu * mu;
    const float rstd = rsqrtf(var + EPS_);
    half8 oh, ol;
#pragma unroll
    for (int j = 0; j < 8; j++) {
        const float y = (v[j] - mu) * rstd * pnw[c0 + j] + pnb[c0 + j];
        const _Float16 hy = (_Float16)y;
        oh[j] = hy;
        ol[j] = (_Float16)(y - (float)hy);
    }
    *(half8*)(XNhi + (size_t)m * C_DIM + c0) = oh;
    *(half8*)(XNlo + (size_t)m * C_DIM + c0) = ol;
}

// ======================================================================
extern "C" void kernel_launch(void* const* d_in, const int* in_sizes, int n_in,
                              void* d_out, int out_size, void* d_ws, size_t ws_size,
                              hipStream_t stream)
{
    (void)in_sizes; (void)n_in; (void)out_size;
    const float* hidden  = (const float*)d_in[0];
    const float* Wq      = (const float*)d_in[2];
    const float* Wk      = (const float*)d_in[3];
    const float* Wv      = (const float*)d_in[4];
    const float* Wo      = (const float*)d_in[5];
    const float* W1      = (const float*)d_in[6];
    const float* b1      = (const float*)d_in[7];
    const float* wlr     = (const float*)d_in[8];
    const float* lr_bias = (const float*)d_in[9];
    const float* lt      = (const float*)d_in[10];
    const float* lnw     = (const float*)d_in[11];
    const float* lnb     = (const float*)d_in[12];
    const float* pnw     = (const float*)d_in[13];
    const float* pnb     = (const float*)d_in[14];

    const size_t TEN = (size_t)B_DIM * NHEADS * L_SEQ * HDIM;  // 16777216
    float* XQ  = (float*)d_ws;
    float* XK  = XQ + TEN;
    float* XVo = XK + TEN;
    float* LRS = XVo + TEN;                      // 262144 floats
    _Float16* Ahi = (_Float16*)(LRS + 262144);   // pre-split hidden (hi)
    _Float16* Alo = Ahi + TEN;                   // pre-split hidden (lo)
    const size_t needBytes = (3 * TEN + 262144) * 4 + TEN * 4;  // ~257 MB
    const int useAsplit = (ws_size >= needBytes) ? 1 : 0;
    const dim3 blk(256);

    // Weight-split scratch lives in d_out (25.2 MB) until the final GEMM.
    _Float16* BThi = (_Float16*)d_out;
    _Float16* BTlo = BThi + (size_t)C_DIM * C_DIM;

    lr_kernel<<<dim3(B_DIM * L_SEQ), blk, 0, stream>>>(hidden, wlr, lr_bias, LRS);
    if (useAsplit)
        asplit_kernel<<<dim3(4096), blk, 0, stream>>>(hidden, Ahi, Alo);

    const float* Wmats[3] = {Wq, Wk, Wv};
    float* outs[3] = {XQ, XK, XVo};
    for (int p = 0; p < 3; p++) {
        wtrans_kernel<<<dim3(64, 64), blk, 0, stream>>>(Wmats[p], BThi, BTlo, C_DIM);
        if (useAsplit)
            gemm8<<<dim3(512), dim3(512), 0, stream>>>(Ahi, Alo, BThi, BTlo,
                                                       outs[p], C_DIM,
                                                       0, (p < 2) ? 1 : 0);
        else
            gemm_f32<<<dim3(16, 64), blk, 0, stream>>>(hidden, BThi, BTlo,
                                                       outs[p], 0, (p < 2) ? 1 : 0);
    }
    scan_mfma<<<dim3(B_DIM * NHEADS), blk, 0, stream>>>(XQ, XK, XVo, LRS,
                                                        W1, b1, lt, lnw, lnb);
    // XQ region is dead now: reuse it for the pre-split post-norm output.
    _Float16* XNhi = (_Float16*)XQ;
    _Float16* XNlo = XNhi + TEN;
    _Float16* WThi = (_Float16*)XK;
    _Float16* WTlo = WThi + (size_t)OUT_DIM * C_DIM;
    postln_kernel<<<dim3(B_DIM * L_SEQ), blk, 0, stream>>>(XVo, pnw, pnb,
                                                           XNhi, XNlo);
    wtrans_kernel<<<dim3(24, 64), blk, 0, stream>>>(Wo, WThi, WTlo, OUT_DIM);
    gemm8<<<dim3(192), dim3(512), 0, stream>>>(XNhi, XNlo, WThi, WTlo,
                                               (float*)d_out, OUT_DIM, 1, 0);
}

// Round 6
// 1396.279 us; speedup vs baseline: 1.0194x; 1.0194x over previous
//
#include <hip/hip_runtime.h>
#include <cstddef>
#include <cstdint>

// Problem constants
#define B_DIM   4
#define L_SEQ   2048
#define C_DIM   2048
#define OUT_DIM 768
#define NHEADS  32
#define HDIM    64
#define MBS_    16
#define NMINI   128
#define EPS_    1e-6f

typedef _Float16 half8 __attribute__((ext_vector_type(8)));
typedef _Float16 half4 __attribute__((ext_vector_type(4)));
typedef float floatx4 __attribute__((ext_vector_type(4)));

__device__ __forceinline__ void glds16(const void* g, void* l) {
    __builtin_amdgcn_global_load_lds(
        (const __attribute__((address_space(1))) uint32_t*)g,
        (__attribute__((address_space(3))) uint32_t*)l, 16, 0, 0);
}

__device__ __forceinline__ void split8(const float4 a, const float4 b,
                                       half8& hi, half8& lo) {
    const float x[8] = {a.x, a.y, a.z, a.w, b.x, b.y, b.z, b.w};
#pragma unroll
    for (int e = 0; e < 8; e++) {
        const _Float16 h = (_Float16)x[e];
        hi[e] = h;
        lo[e] = (_Float16)(x[e] - (float)h);
    }
}

__device__ __forceinline__ void split4(const float4 a, half4& hi, half4& lo) {
    const float x[4] = {a.x, a.y, a.z, a.w};
#pragma unroll
    for (int e = 0; e < 4; e++) {
        const _Float16 h = (_Float16)x[e];
        hi[e] = h;
        lo[e] = (_Float16)(x[e] - (float)h);
    }
}

// pack fp32 -> (hi fp16, lo fp16) in one dword (H low, L high)
__device__ __forceinline__ uint32_t pack_hl(float v) {
    const _Float16 h = (_Float16)v;
    const _Float16 l = (_Float16)(v - (float)h);
    union { _Float16 f[2]; uint32_t u; } p;
    p.f[0] = h; p.f[1] = l;
    return p.u;
}

// swap the (H,L) halves inside each dword of a half8 (rotate-16)
__device__ __forceinline__ half8 pairswap(half8 v) {
    union { half8 h; uint32_t u[4]; } a, b;
    a.h = v;
#pragma unroll
    for (int e = 0; e < 4; e++) b.u[e] = (a.u[e] >> 16) | (a.u[e] << 16);
    return b.h;
}

// DPP-based 16-lane (row) reduction: quad xor1, xor2, then row_ror 4, 8.
template<int CTRL>
__device__ __forceinline__ float dpp_add(float v) {
    const int x = __builtin_amdgcn_update_dpp(0, __float_as_int(v), CTRL, 0xF, 0xF, false);
    return v + __int_as_float(x);
}
__device__ __forceinline__ float red16(float v) {
    v = dpp_add<0xB1>(v);   // quad_perm(1,0,3,2) : xor 1
    v = dpp_add<0x4E>(v);   // quad_perm(2,3,0,1) : xor 2
    v = dpp_add<0x124>(v);  // row_ror:4
    v = dpp_add<0x128>(v);  // row_ror:8
    return v;
}

// barrier that drains ONLY LDS counters; vmem (prefetch loads / output
// stores) stay in flight across it.
__device__ __forceinline__ void bar_lgkm() {
    asm volatile("s_waitcnt lgkmcnt(0)\n\ts_barrier" ::: "memory");
}

// ======================================================================
// Deep-pipelined MFMA GEMM (R4 coarse schedule — best measured).
// 256x128 tile, BK=32, triple-buffered LDS, counted vmcnt(6), one barrier
// per K-step, setprio around MFMA cluster. A,B pre-split fp16 hi/lo.
// mode 0 = fused QKV store: p = n>>11 selects XQ/XK/XVo (contiguous,
// stride 16777216 floats); RoPE applied iff n < 4096.
// mode 1 = plain [M][OUT_DIM] store.
// ======================================================================
__global__ __launch_bounds__(512)
void gemm8(const _Float16* __restrict__ Ahi, const _Float16* __restrict__ Alo,
           const _Float16* __restrict__ Bhi, const _Float16* __restrict__ Blo,
           float* __restrict__ Cout, int Ndim, int mode, int doRope)
{
    __shared__ __align__(16) _Float16 sAh[3][8192];  // [256][32]
    __shared__ __align__(16) _Float16 sAl[3][8192];
    __shared__ __align__(16) _Float16 sBh[3][4096];  // [128][32]
    __shared__ __align__(16) _Float16 sBl[3][4096];
    const int tid = threadIdx.x;
    const int nbx = Ndim >> 7;            // N / 128
    const int nwg = gridDim.x;            // multiple of 8
    int lin = blockIdx.x;
    lin = (lin & 7) * (nwg >> 3) + (lin >> 3);   // XCD swizzle (bijective)
    const int m0 = (lin / nbx) * 256;
    const int n0 = (lin % nbx) * 128;
    const int K = 2048;

    // staging addresses: LDS dest linear (chunk*16B), global src pre-swizzled
    size_t gA[2];
    int lA[2];
#pragma unroll
    for (int X = 0; X < 2; X++) {
        const int c = X * 512 + tid;
        const int row = c >> 2, s = c & 3;
        const int ks = s ^ ((row >> 1) & 3);
        gA[X] = (size_t)(m0 + row) * K + ks * 8;
        lA[X] = c * 8;
    }
    size_t gB;
    int lB;
    {
        const int row = tid >> 2, s = tid & 3;
        const int ks = s ^ ((row >> 1) & 3);
        gB = (size_t)(n0 + row) * K + ks * 8;
        lB = tid * 8;
    }

    const int lane = tid & 63, q = lane >> 4, lc = lane & 15;
    const int w = tid >> 6, wm = w >> 1, wn = w & 1;
    int offA[4], offB[4];
#pragma unroll
    for (int i = 0; i < 4; i++) {
        const int rA = wm * 64 + i * 16 + lc;
        offA[i] = rA * 32 + ((q ^ ((rA >> 1) & 3)) << 3);
    }
#pragma unroll
    for (int j = 0; j < 4; j++) {
        const int rB = wn * 64 + j * 16 + lc;
        offB[j] = rB * 32 + ((q ^ ((rB >> 1) & 3)) << 3);
    }

    floatx4 acc[4][4];
#pragma unroll
    for (int i = 0; i < 4; i++)
#pragma unroll
        for (int j = 0; j < 4; j++) acc[i][j] = (floatx4)0.0f;

#define STAGE(T)                                                         \
    {                                                                    \
        const int b_ = (T) % 3;                                          \
        const int ko_ = (T) * 32;                                        \
        glds16(Ahi + gA[0] + ko_, &sAh[b_][lA[0]]);                      \
        glds16(Alo + gA[0] + ko_, &sAl[b_][lA[0]]);                      \
        glds16(Ahi + gA[1] + ko_, &sAh[b_][lA[1]]);                      \
        glds16(Alo + gA[1] + ko_, &sAl[b_][lA[1]]);                      \
        glds16(Bhi + gB + ko_,    &sBh[b_][lB]);                         \
        glds16(Blo + gB + ko_,    &sBl[b_][lB]);                         \
    }

#define FRAGS(B_)                                                        \
    half8 ah[4], al[4], bh[4], bl[4];                                    \
    _Pragma("unroll")                                                    \
    for (int i = 0; i < 4; i++) {                                        \
        ah[i] = *(const half8*)&sAh[B_][offA[i]];                        \
        al[i] = *(const half8*)&sAl[B_][offA[i]];                        \
    }                                                                    \
    _Pragma("unroll")                                                    \
    for (int j = 0; j < 4; j++) {                                        \
        bh[j] = *(const half8*)&sBh[B_][offB[j]];                        \
        bl[j] = *(const half8*)&sBl[B_][offB[j]];                        \
    }

#define MFMAS                                                            \
    __builtin_amdgcn_s_setprio(1);                                       \
    _Pragma("unroll")                                                    \
    for (int i = 0; i < 4; i++)                                          \
        _Pragma("unroll")                                                \
        for (int j = 0; j < 4; j++) {                                    \
            acc[i][j] = __builtin_amdgcn_mfma_f32_16x16x32_f16(ah[i], bh[j], acc[i][j], 0, 0, 0); \
            acc[i][j] = __builtin_amdgcn_mfma_f32_16x16x32_f16(ah[i], bl[j], acc[i][j], 0, 0, 0); \
            acc[i][j] = __builtin_amdgcn_mfma_f32_16x16x32_f16(al[i], bh[j], acc[i][j], 0, 0, 0); \
        }                                                                \
    __builtin_amdgcn_s_setprio(0);

    // prologue: stage tiles 0 and 1; publish tile 0
    STAGE(0)
    STAGE(1)
    asm volatile("s_waitcnt vmcnt(6) lgkmcnt(0)\n\ts_barrier" ::: "memory");

    // main loop: tiles 0..61; stage t+2; wait 6 (t+1's loads done)
    for (int t = 0; t < 62; t++) {
        const int b = t % 3;
        FRAGS(b)
        STAGE(t + 2)
        MFMAS
        asm volatile("s_waitcnt vmcnt(6) lgkmcnt(0)\n\ts_barrier" ::: "memory");
    }
    // tile 62: no staging left; drain all, publish tile 63
    {
        FRAGS(2)
        MFMAS
        asm volatile("s_waitcnt vmcnt(0) lgkmcnt(0)\n\ts_barrier" ::: "memory");
    }
    // tile 63: compute only
    {
        FRAGS(0)
        MFMAS
    }
#undef STAGE
#undef FRAGS
#undef MFMAS

    float cs[4][4], sn[4][4];
    if (doRope) {
#pragma unroll
        for (int j = 0; j < 4; j++) {
            const int ii = ((j * 16 + lc) & 63) >> 1;
            const float invf = expf(-(float)ii * 0.28782313662425574f);
#pragma unroll
            for (int r = 0; r < 4; r++) {
                const float ang = (float)(q * 4 + r) * invf;
                sincosf(ang, &sn[j][r], &cs[j][r]);
            }
        }
    }
    const int oddcol = lc & 1;
#pragma unroll
    for (int i = 0; i < 4; i++) {
#pragma unroll
        for (int j = 0; j < 4; j++) {
            floatx4 v = acc[i][j];
            const int n = n0 + wn * 64 + j * 16 + lc;
            if (doRope && n < 4096) {
#pragma unroll
                for (int r = 0; r < 4; r++) {
                    const float partner = __shfl_xor(v[r], 1);
                    v[r] = v[r] * cs[j][r] + partner * (oddcol ? sn[j][r] : -sn[j][r]);
                }
            }
            if (mode == 0) {
                const int p = n >> 11;
                const int h = (n >> 6) & 31, d = n & 63;
#pragma unroll
                for (int r = 0; r < 4; r++) {
                    const int m = m0 + wm * 64 + i * 16 + q * 4 + r;
                    const int b = m >> 11, li = m & 2047;
                    Cout[(size_t)p * 16777216 +
                         ((size_t)(b * 32 + h) * 2048 + li) * 64 + d] = v[r];
                }
            } else {
#pragma unroll
                for (int r = 0; r < 4; r++) {
                    const int m = m0 + wm * 64 + i * 16 + q * 4 + r;
                    Cout[(size_t)m * OUT_DIM + n] = v[r];
                }
            }
        }
    }
}

// ======================================================================
// Fallback MFMA GEMM (fp32 A split on the fly) — only used if workspace
// is too small for the pre-split path. 128x128 tile, 256 threads.
// ======================================================================
__global__ __launch_bounds__(256)
void gemm_f32(const float* __restrict__ A,
              const _Float16* __restrict__ Bhi, const _Float16* __restrict__ Blo,
              float* __restrict__ Cout, int mode, int doRope)
{
    __shared__ __align__(16) float    sA[4096];
    __shared__ __align__(16) _Float16 sBhi[4096];
    __shared__ __align__(16) _Float16 sBlo[4096];
    const int tid = threadIdx.x;
    const int m0 = blockIdx.y * 128, n0 = blockIdx.x * 128;
    const int K = 2048;

    size_t gA[4]; float* lA[4];
#pragma unroll
    for (int I = 0; I < 4; I++) {
        const int c = I * 256 + tid;
        const int row = c >> 3, seg = (c & 7) ^ (row & 7);
        gA[I] = (size_t)(m0 + row) * K + seg * 4;
        lA[I] = &sA[c * 4];
    }
    size_t gB[2]; _Float16 *lBh[2], *lBl[2];
#pragma unroll
    for (int I = 0; I < 2; I++) {
        const int c = I * 256 + tid;
        const int row = c >> 2, seg = (c & 3) ^ ((row >> 1) & 3);
        gB[I] = (size_t)(n0 + row) * K + seg * 8;
        lBh[I] = &sBhi[c * 8];
        lBl[I] = &sBlo[c * 8];
    }

    const int lane = tid & 63, quad = lane >> 4, lc = lane & 15;
    const int wv = tid >> 6, wm = wv & 1, wn = wv >> 1;
    int offA0[4], offA1[4], offB[4];
#pragma unroll
    for (int i = 0; i < 4; i++) {
        const int rA = wm * 64 + i * 16 + lc;
        offA0[i] = (rA * 8 + ((2 * quad)     ^ (rA & 7))) * 4;
        offA1[i] = (rA * 8 + ((2 * quad + 1) ^ (rA & 7))) * 4;
    }
#pragma unroll
    for (int j = 0; j < 4; j++) {
        const int rB = wn * 64 + j * 16 + lc;
        offB[j] = (rB * 4 + (quad ^ ((rB >> 1) & 3))) * 8;
    }

    floatx4 acc[4][4];
#pragma unroll
    for (int i = 0; i < 4; i++)
#pragma unroll
        for (int j = 0; j < 4; j++) acc[i][j] = (floatx4)0.0f;

    for (int k0 = 0; k0 < K; k0 += 32) {
        __syncthreads();
#pragma unroll
        for (int I = 0; I < 4; I++) glds16(A + gA[I] + k0, lA[I]);
#pragma unroll
        for (int I = 0; I < 2; I++) {
            glds16(Bhi + gB[I] + k0, lBh[I]);
            glds16(Blo + gB[I] + k0, lBl[I]);
        }
        __syncthreads();

        half8 ah[4], al[4], bh[4], bl[4];
#pragma unroll
        for (int i = 0; i < 4; i++) {
            const float4 va = *(const float4*)&sA[offA0[i]];
            const float4 vb = *(const float4*)&sA[offA1[i]];
            split8(va, vb, ah[i], al[i]);
        }
#pragma unroll
        for (int j = 0; j < 4; j++) {
            bh[j] = *(const half8*)&sBhi[offB[j]];
            bl[j] = *(const half8*)&sBlo[offB[j]];
        }
#pragma unroll
        for (int i = 0; i < 4; i++)
#pragma unroll
            for (int j = 0; j < 4; j++) {
                acc[i][j] = __builtin_amdgcn_mfma_f32_16x16x32_f16(ah[i], bh[j], acc[i][j], 0, 0, 0);
                acc[i][j] = __builtin_amdgcn_mfma_f32_16x16x32_f16(ah[i], bl[j], acc[i][j], 0, 0, 0);
                acc[i][j] = __builtin_amdgcn_mfma_f32_16x16x32_f16(al[i], bh[j], acc[i][j], 0, 0, 0);
            }
    }

    float cs[4][4], sn[4][4];
    if (doRope) {
#pragma unroll
        for (int j = 0; j < 4; j++) {
            const int ii = ((j * 16 + lc) & 63) >> 1;
            const float invf = expf(-(float)ii * 0.28782313662425574f);
#pragma unroll
            for (int r = 0; r < 4; r++) {
                const float ang = (float)(quad * 4 + r) * invf;
                sincosf(ang, &sn[j][r], &cs[j][r]);
            }
        }
    }
    const int oddcol = lc & 1;
#pragma unroll
    for (int i = 0; i < 4; i++) {
#pragma unroll
        for (int j = 0; j < 4; j++) {
            floatx4 v = acc[i][j];
            if (doRope) {
#pragma unroll
                for (int r = 0; r < 4; r++) {
                    const float partner = __shfl_xor(v[r], 1);
                    v[r] = v[r] * cs[j][r] + partner * (oddcol ? sn[j][r] : -sn[j][r]);
                }
            }
            const int n = n0 + wn * 64 + j * 16 + lc;
            if (mode == 0) {
                const int h = (n >> 6) & 31, d = n & 63;
#pragma unroll
                for (int r = 0; r < 4; r++) {
                    const int m = m0 + wm * 64 + i * 16 + quad * 4 + r;
                    const int b = m >> 11, li = m & 2047;
                    Cout[((size_t)(b * 32 + h) * 2048 + li) * 64 + d] = v[r];
                }
            } else {
#pragma unroll
                for (int r = 0; r < 4; r++) {
                    const int m = m0 + wm * 64 + i * 16 + quad * 4 + r;
                    Cout[(size_t)m * OUT_DIM + n] = v[r];
                }
            }
        }
    }
}

// ======================================================================
// Weight transpose + split, generic (fallback path)
// ======================================================================
__global__ __launch_bounds__(256)
void wtrans_kernel(const float* __restrict__ W, _Float16* __restrict__ BThi,
                   _Float16* __restrict__ BTlo, int Nw)
{
    __shared__ float tile[32][33];
    const int t = threadIdx.x, tx = t & 31, ty = t >> 5;
    const int n0 = blockIdx.x * 32, k0 = blockIdx.y * 32;
    const int K = 2048;
#pragma unroll
    for (int r = 0; r < 4; r++)
        tile[ty + r * 8][tx] = W[(size_t)(k0 + ty + r * 8) * Nw + n0 + tx];
    __syncthreads();
#pragma unroll
    for (int r = 0; r < 4; r++) {
        const float val = tile[tx][ty + r * 8];
        const _Float16 hh = (_Float16)val;
        const size_t o = (size_t)(n0 + ty + r * 8) * K + k0 + tx;
        BThi[o] = hh;
        BTlo[o] = (_Float16)(val - (float)hh);
    }
}

// ======================================================================
// All 4 weight transposes in one launch:
//  blocks [0, 12288): Wq/Wk/Wv -> BT (p = id/4096), Nw = 2048
//  blocks [12288, 13824): Wo -> WT, Nw = 768
// ======================================================================
__global__ __launch_bounds__(256)
void wtrans_all(const float* __restrict__ Wq, const float* __restrict__ Wk,
                const float* __restrict__ Wv, const float* __restrict__ Wo,
                _Float16* __restrict__ BThi, _Float16* __restrict__ BTlo,
                _Float16* __restrict__ WThi, _Float16* __restrict__ WTlo)
{
    __shared__ float tile[32][33];
    const int t = threadIdx.x, tx = t & 31, ty = t >> 5;
    const int id = blockIdx.x;
    const float* W;
    _Float16 *dh, *dl;
    int Nw, bx, by;
    if (id < 12288) {
        const int p = id >> 12;
        const int r = id & 4095;
        bx = r & 63; by = r >> 6;
        W = (p == 0) ? Wq : (p == 1) ? Wk : Wv;
        dh = BThi + (size_t)p * C_DIM * C_DIM;
        dl = BTlo + (size_t)p * C_DIM * C_DIM;
        Nw = C_DIM;
    } else {
        const int r = id - 12288;
        bx = r % 24; by = r / 24;
        W = Wo; dh = WThi; dl = WTlo; Nw = OUT_DIM;
    }
    const int n0 = bx * 32, k0 = by * 32;
    const int K = 2048;
#pragma unroll
    for (int r = 0; r < 4; r++)
        tile[ty + r * 8][tx] = W[(size_t)(k0 + ty + r * 8) * Nw + n0 + tx];
    __syncthreads();
#pragma unroll
    for (int r = 0; r < 4; r++) {
        const float val = tile[tx][ty + r * 8];
        const _Float16 hh = (_Float16)val;
        const size_t o = (size_t)(n0 + ty + r * 8) * K + k0 + tx;
        dh[o] = hh;
        dl[o] = (_Float16)(val - (float)hh);
    }
}

// ======================================================================
// ttt_lr sigmoid + (optional) hidden-row fp16 hi/lo pre-split.
// The block already stages the full hidden row in LDS; splitting it here
// removes the separate asplit kernel (saves a 32 MB re-read + a launch).
// ======================================================================
__global__ __launch_bounds__(256)
void lr_kernel(const float* __restrict__ hidden, const float* __restrict__ wlr,
               const float* __restrict__ lr_bias, float* __restrict__ lrs,
               _Float16* __restrict__ Ahi, _Float16* __restrict__ Alo)
{
    __shared__ float sRow[2048];
    __shared__ float sPart[32][9];
    const int m = blockIdx.x;
    const int t = threadIdx.x;
    const float* row = hidden + (size_t)m * C_DIM;
#pragma unroll
    for (int j = 0; j < 8; j++) sRow[t + j * 256] = row[t + j * 256];
    __syncthreads();
    if (Ahi) {
        const float4 a = *(const float4*)(sRow + t * 8);
        const float4 b = *(const float4*)(sRow + t * 8 + 4);
        half8 hh, ll;
        split8(a, b, hh, ll);
        *(half8*)(Ahi + (size_t)m * C_DIM + t * 8) = hh;
        *(half8*)(Alo + (size_t)m * C_DIM + t * 8) = ll;
    }
    const int h = t >> 3, p = t & 7;
    const float* w = wlr + (size_t)h * C_DIM;
    float s = 0.0f;
#pragma unroll 8
    for (int k = 0; k < 64; k++) {
        const int c = k * 32 + p * 4;
        const float4 a = *(const float4*)(sRow + c);
        const float4 b = *(const float4*)(w + c);
        s += a.x * b.x + a.y * b.y + a.z * b.z + a.w * b.w;
    }
    sPart[h][p] = s;
    __syncthreads();
    if (t < 32) {
        float v = 0.0f;
#pragma unroll
        for (int p2 = 0; p2 < 8; p2++) v += sPart[t][p2];
        v += lr_bias[t];
        const float sig = 1.0f / (1.0f + expf(-v));
        lrs[((size_t)(m >> 11) * NHEADS + t) * L_SEQ + (m & 2047)] = sig;
    }
}

// ======================================================================
// MFMA TTT scan v4 (unchanged from R5): 2 lgkm-only barriers/step.
// ======================================================================
__global__ __launch_bounds__(256, 1)
void scan_mfma(const float* __restrict__ XQ, const float* __restrict__ XK,
               float* __restrict__ XVo, const float* __restrict__ LRS,
               const float* __restrict__ W1i, const float* __restrict__ b1i,
               const float* __restrict__ lt, const float* __restrict__ lnw,
               const float* __restrict__ lnb)
{
    __shared__ __align__(16) _Float16 sXqH[1024], sXqL[1024];   // [16][64] hi/lo
    __shared__ __align__(16) _Float16 sXkH[1024], sXkL[1024];   // [16][64] hi/lo
    __shared__ __align__(16) float    sTgt[16 * 68];            // xv - xk, plain
    __shared__ __align__(16) float    sXq32[2][16 * 68];        // fp32 xq, dbuf
    __shared__ __align__(16) _Float16 sW1H[4096], sW1L[4096];   // [64 n][64 k]
    __shared__ __align__(16) uint32_t sKT[2][64 * 20];          // packed XkT, dbuf
    __shared__ __align__(16) uint32_t sCf[16 * 20];             // packed coeff
    __shared__ __align__(16) float sRedA[16 * 36];              // 6 sums x 4 waves
    __shared__ __align__(16) float sRedC[16 * 12];              // 2 sums x 4 waves
    __shared__ __align__(16) float sEta[16];
    __shared__ float sB1[64];

    const int bh = blockIdx.x, h = bh & 31;
    const int t = threadIdx.x;
    const int lane = t & 63, q = lane >> 4, lc = lane & 15;
    const int w = t >> 6;
    const int col = w * 16 + lc;     // this lane's output column n
    const int iRow = t >> 4;         // staging row (0..15)
    const int m = t & 15;            // staging col group

    if (t < 64) sB1[t] = b1i[h * 64 + t];

    // W1 state regs: w1s[t4][r] = W1T[16w+4q+r][16t4+lc]
    float w1s[4][4];
#pragma unroll
    for (int t4 = 0; t4 < 4; t4++)
#pragma unroll
        for (int r = 0; r < 4; r++) {
            const float v = W1i[h * 4096 + (16 * t4 + lc) * 64 + (16 * w + 4 * q + r)];
            w1s[t4][r] = v;
            const int nn = 16 * w + 4 * q + r, k = 16 * t4 + lc;
            const int off = nn * 64 + ((((k >> 3) ^ (nn & 7)) << 3) | (k & 7));
            const _Float16 hh = (_Float16)v;
            sW1H[off] = hh; sW1L[off] = (_Float16)(v - (float)hh);
        }

    const float gamC = lnw[h * 64 + col], betC = lnb[h * 64 + col];
    const float g2c = gamC * gamC;
    // sum of gamma^2 over the 64 cols (constant for all rows/steps)
    float sumG2 = 0.0f;
#pragma unroll
    for (int d0 = 0; d0 < 16; d0++) {
        const float4 gv = *(const float4*)(lnw + h * 64 + d0 * 4);
        sumG2 += gv.x * gv.x + gv.y * gv.y + gv.z * gv.z + gv.w * gv.w;
    }
    float tokR[4];
#pragma unroll
    for (int r = 0; r < 4; r++)
        tokR[r] = fmaxf(1.0f / (float)(4 * q + r + 1) + lt[4 * q + r], 0.0f);
    const float tok15 = fmaxf(1.0f / 16.0f + lt[15], 0.0f);

    __syncthreads();

    const size_t base = (size_t)bh * L_SEQ * HDIM;
    const float* xq_g = XQ + base;
    const float* xk_g = XK + base;
    float* xv_g = XVo + base;
    const float* lr_g = LRS + (size_t)bh * L_SEQ;

    // preload minibatch 0 (thread t: row t>>4, cols 4m..4m+3)
    float4 cq = *(const float4*)(xq_g + t * 4);
    float4 ck = *(const float4*)(xk_g + t * 4);
    float4 cv = *(const float4*)(xv_g + t * 4);
    float clr = lr_g[m];

    const int rw = 16 * w + lc;
    // per-thread staging constants
    const int stOff = iRow * 64 + ((((m >> 1) ^ (iRow & 7)) << 3) | ((m & 1) << 2));
    const int gkm = (m ^ (m >> 2)) & 3;
    const int ktWb = 4 * (w ^ gkm) + q;          // sKT write col base (j = iRow)

    float z2p[4] = {0.0f, 0.0f, 0.0f, 0.0f};     // carried Zbar(n-1)+b1

    for (int n = 0; n < NMINI; n++) {
        const int buf = n & 1;
        // prefetch next minibatch FIRST (stays in flight across barriers)
        const int np = (n + 1) & (NMINI - 1);
        const float4 nq = *(const float4*)(xq_g + np * 1024 + t * 4);
        const float4 nk = *(const float4*)(xk_g + np * 1024 + t * 4);
        const float4 nv = *(const float4*)(xv_g + np * 1024 + t * 4);
        const float nlr = lr_g[np * 16 + m];
        // ---- stage current minibatch ----
        {
            half4 hq, lq, hk, lk;
            split4(cq, hq, lq);
            split4(ck, hk, lk);
            *(half4*)&sXqH[stOff] = hq;
            *(half4*)&sXqL[stOff] = lq;
            *(half4*)&sXkH[stOff] = hk;
            *(half4*)&sXkL[stOff] = lk;
            const float4 tg = make_float4(cv.x - ck.x, cv.y - ck.y,
                                          cv.z - ck.z, cv.w - ck.w);
            *(float4*)&sTgt[iRow * 68 + m * 4] = tg;
            *(float4*)&sXq32[buf][iRow * 68 + m * 4] = cq;
            const float kvv[4] = {ck.x, ck.y, ck.z, ck.w};
#pragma unroll
            for (int i2 = 0; i2 < 4; i2++)
                sKT[buf][(4 * m + i2) * 20 + ktWb] = pack_hl(kvv[i2]);
        }
        if (t < 16) sEta[t] = clr * (1.0f / 64.0f);
        bar_lgkm();   // A

        // ---- deferred out-store for step n-1 ----
        if (n) {
            const int pb = buf ^ 1;
#pragma unroll
            for (int r = 0; r < 4; r++) {
                const int row = 4 * q + r;
                const float4 a = *(const float4*)&sRedC[row * 12];
                const float4 b = *(const float4*)&sRedC[row * 12 + 4];
                const float mu  = (a.x + a.y + a.z + a.w) * (1.0f / 64.0f);
                const float ex2 = (b.x + b.y + b.z + b.w) * (1.0f / 64.0f);
                const float rs  = rsqrtf(ex2 - mu * mu + EPS_);
                const float xqv = sXq32[pb][row * 68 + col];
                xv_g[(n - 1) * 1024 + row * 64 + col] =
                    xqv + gamC * ((z2p[r] - mu) * rs) + betC;
            }
        }

        const float b1c = sB1[col];
        const float4 ev = *(const float4*)&sEta[4 * q];
        const float evv[4] = {ev.x, ev.y, ev.z, ev.w};

        // ---- forward fragments ----
        half8 qh[2], ql[2], kh[2], kl[2], wh[2], wl[2];
#pragma unroll
        for (int f = 0; f < 2; f++) {
            const int cx = ((4 * f + q) ^ (lc & 7)) << 3;
            qh[f] = *(const half8*)&sXqH[lc * 64 + cx];
            ql[f] = *(const half8*)&sXqL[lc * 64 + cx];
            kh[f] = *(const half8*)&sXkH[lc * 64 + cx];
            kl[f] = *(const half8*)&sXkL[lc * 64 + cx];
            const int cw = ((4 * f + q) ^ (rw & 7)) << 3;
            wh[f] = *(const half8*)&sW1H[rw * 64 + cw];
            wl[f] = *(const half8*)&sW1L[rw * 64 + cw];
        }

        // ---- forward MFMAs (split chains: f=0 / f=1 accumulate apart) ----
        floatx4 z1a = (floatx4)0.0f, z1b = (floatx4)0.0f;
        floatx4 zb0 = (floatx4)0.0f, zb1 = (floatx4)0.0f;
        z1a = __builtin_amdgcn_mfma_f32_16x16x32_f16(kh[0], wh[0], z1a, 0, 0, 0);
        z1a = __builtin_amdgcn_mfma_f32_16x16x32_f16(kh[0], wl[0], z1a, 0, 0, 0);
        z1a = __builtin_amdgcn_mfma_f32_16x16x32_f16(kl[0], wh[0], z1a, 0, 0, 0);
        z1b = __builtin_amdgcn_mfma_f32_16x16x32_f16(kh[1], wh[1], z1b, 0, 0, 0);
        z1b = __builtin_amdgcn_mfma_f32_16x16x32_f16(kh[1], wl[1], z1b, 0, 0, 0);
        z1b = __builtin_amdgcn_mfma_f32_16x16x32_f16(kl[1], wh[1], z1b, 0, 0, 0);
        zb0 = __builtin_amdgcn_mfma_f32_16x16x32_f16(qh[0], wh[0], zb0, 0, 0, 0);
        zb0 = __builtin_amdgcn_mfma_f32_16x16x32_f16(qh[0], wl[0], zb0, 0, 0, 0);
        zb0 = __builtin_amdgcn_mfma_f32_16x16x32_f16(ql[0], wh[0], zb0, 0, 0, 0);
        zb1 = __builtin_amdgcn_mfma_f32_16x16x32_f16(qh[1], wh[1], zb1, 0, 0, 0);
        zb1 = __builtin_amdgcn_mfma_f32_16x16x32_f16(qh[1], wl[1], zb1, 0, 0, 0);
        zb1 = __builtin_amdgcn_mfma_f32_16x16x32_f16(ql[1], wh[1], zb1, 0, 0, 0);
        // wave 0: Attn + packed coeff (read after barrier B)
        if (w == 0) {
            const float etaLC = sEta[lc];
            floatx4 at0 = (floatx4)0.0f, at1 = (floatx4)0.0f;
            at0 = __builtin_amdgcn_mfma_f32_16x16x32_f16(qh[0], kh[0], at0, 0, 0, 0);
            at0 = __builtin_amdgcn_mfma_f32_16x16x32_f16(qh[0], kl[0], at0, 0, 0, 0);
            at0 = __builtin_amdgcn_mfma_f32_16x16x32_f16(ql[0], kh[0], at0, 0, 0, 0);
            at1 = __builtin_amdgcn_mfma_f32_16x16x32_f16(qh[1], kh[1], at1, 0, 0, 0);
            at1 = __builtin_amdgcn_mfma_f32_16x16x32_f16(qh[1], kl[1], at1, 0, 0, 0);
            at1 = __builtin_amdgcn_mfma_f32_16x16x32_f16(ql[1], kh[1], at1, 0, 0, 0);
#pragma unroll
            for (int r = 0; r < 4; r++) {
                const int i = 4 * q + r;
                const float atv = at0[r] + at1[r];
                const float cfv = (lc <= i) ? -tokR[r] * etaLC * (atv + 1.0f) : 0.0f;
                sCf[i * 20 + 4 * ((lc >> 2) ^ q) + (lc & 3)] = pack_hl(cfv);
            }
        }

        // ---- merged Z1 + grad stats: 6 sums, one barrier ----
        float z[4], cE[4];
        float sz[4], szz[4], sgz[4], sgzz[4], sc[4], scz[4];
#pragma unroll
        for (int r = 0; r < 4; r++) {
            const int row = 4 * q + r;
            z[r] = z1a[r] + z1b[r] + b1c;
            const float tgt = sTgt[row * 68 + col];
            cE[r] = gamC * (betC - tgt);
            const float zz = z[r] * z[r];
            sz[r]   = red16(z[r]);
            szz[r]  = red16(zz);
            sgz[r]  = red16(g2c * z[r]);
            sgzz[r] = red16(g2c * zz);
            sc[r]   = red16(cE[r]);
            scz[r]  = red16(cE[r] * z[r]);
        }
        if (lc == 0) {
#pragma unroll
            for (int r = 0; r < 4; r++) {
                const int rb = (4 * q + r) * 36;
                sRedA[rb + 0  + w] = sz[r];
                sRedA[rb + 4  + w] = szz[r];
                sRedA[rb + 8  + w] = sgz[r];
                sRedA[rb + 12 + w] = sgzz[r];
                sRedA[rb + 16 + w] = sc[r];
                sRedA[rb + 20 + w] = scz[r];
            }
        }
        bar_lgkm();   // B

        // operand loads (cross-wave data, ordered by B)
        half8 ktp[4];
#pragma unroll
        for (int t4 = 0; t4 < 4; t4++) {
            const int gkr = ((lc >> 2) ^ t4) & 3;
            ktp[t4] = *(const half8*)&sKT[buf][(16 * t4 + lc) * 20 + 4 * (q ^ gkr)];
        }
        const half8 cfp = *(const half8*)&sCf[lc * 20 + 4 * (q ^ (lc >> 2))];

        // finish stats, closed-form G1/G2, grad
        float gr[4];
#pragma unroll
        for (int r = 0; r < 4; r++) {
            const int rb = (4 * q + r) * 36;
            const float4 a0 = *(const float4*)&sRedA[rb + 0];
            const float4 a1 = *(const float4*)&sRedA[rb + 4];
            const float4 a2 = *(const float4*)&sRedA[rb + 8];
            const float4 a3 = *(const float4*)&sRedA[rb + 12];
            const float4 a4 = *(const float4*)&sRedA[rb + 16];
            const float4 a5 = *(const float4*)&sRedA[rb + 20];
            const float Sz   = a0.x + a0.y + a0.z + a0.w;
            const float Szz  = a1.x + a1.y + a1.z + a1.w;
            const float Sgz  = a2.x + a2.y + a2.z + a2.w;
            const float Sgzz = a3.x + a3.y + a3.z + a3.w;
            const float Sc   = a4.x + a4.y + a4.z + a4.w;
            const float Scz  = a5.x + a5.y + a5.z + a5.w;
            const float mu  = Sz * (1.0f / 64.0f);
            const float ex2 = Szz * (1.0f / 64.0f);
            const float rs  = rsqrtf(ex2 - mu * mu + EPS_);
            const float G1 = rs * (Sgz - mu * sumG2) + Sc;
            const float G2 = rs * rs * (Sgzz - 2.0f * mu * Sgz + mu * mu * sumG2)
                           + rs * (Scz - mu * Sc);
            const float xh = (z[r] - mu) * rs;
            const float g  = g2c * xh + cE[r];
            gr[r] = (64.0f * g - G1 - xh * G2) * rs * (1.0f / 64.0f);
        }

        // lane-local packed grad fragments (plain + eta-scaled)
        half8 gf, gfl;
#pragma unroll
        for (int r = 0; r < 4; r++) {
            const _Float16 h0 = (_Float16)gr[r];
            gf[2 * r]     = h0;
            gf[2 * r + 1] = (_Float16)(gr[r] - (float)h0);
            const float gl = gr[r] * (tok15 * evv[r]);
            const _Float16 h1 = (_Float16)gl;
            gfl[2 * r]     = h1;
            gfl[2 * r + 1] = (_Float16)(gl - (float)h1);
        }
        const half8 gfs  = pairswap(gf);
        const half8 gfls = pairswap(gfl);

        // Zbar -= coeff @ grad   (full product in 2 MFMAs)
        floatx4 zba;
#pragma unroll
        for (int r = 0; r < 4; r++) zba[r] = zb0[r] + zb1[r];
        zba = __builtin_amdgcn_mfma_f32_16x16x32_f16(cfp, gf,  zba, 0, 0, 0);
        zba = __builtin_amdgcn_mfma_f32_16x16x32_f16(cfp, gfs, zba, 0, 0, 0);
        // W1 -= (eta*grad)^T @ XkT  (2 MFMAs per 16-col block)
#pragma unroll
        for (int t4 = 0; t4 < 4; t4++) {
            floatx4 up = (floatx4)0.0f;
            up = __builtin_amdgcn_mfma_f32_16x16x32_f16(gfl,  ktp[t4], up, 0, 0, 0);
            up = __builtin_amdgcn_mfma_f32_16x16x32_f16(gfls, ktp[t4], up, 0, 0, 0);
#pragma unroll
            for (int r = 0; r < 4; r++) w1s[t4][r] -= up[r];
        }

        // ---- Zbar stats (partials written; read after NEXT barrier A) ----
        float z2[4], p1[4], p2[4];
#pragma unroll
        for (int r = 0; r < 4; r++) {
            z2[r] = zba[r] + b1c;
            p1[r] = red16(z2[r]);
            p2[r] = red16(z2[r] * z2[r]);
        }
        if (lc == 0)
#pragma unroll
            for (int r = 0; r < 4; r++) {
                const int rb = (4 * q + r) * 12;
                sRedC[rb + w]     = p1[r];
                sRedC[rb + 4 + w] = p2[r];
            }

        // ---- b1 update (intra-wave) ----
        {
            float p = gr[0] * evv[0] + gr[1] * evv[1] + gr[2] * evv[2] + gr[3] * evv[3];
            p += __shfl_xor(p, 16);
            p += __shfl_xor(p, 32);
            if (q == 0) sB1[col] -= tok15 * p;
        }
        // ---- W1 regs -> LDS (intra-wave; own rows only) ----
#pragma unroll
        for (int t4 = 0; t4 < 4; t4++)
#pragma unroll
            for (int r = 0; r < 4; r++) {
                const int nn = 16 * w + 4 * q + r, k = 16 * t4 + lc;
                const int off = nn * 64 + ((((k >> 3) ^ (nn & 7)) << 3) | (k & 7));
                const float v = w1s[t4][r];
                const _Float16 hh = (_Float16)v;
                sW1H[off] = hh; sW1L[off] = (_Float16)(v - (float)hh);
            }

#pragma unroll
        for (int r = 0; r < 4; r++) z2p[r] = z2[r];
        cq = nq; ck = nk; cv = nv; clr = nlr;
    }

    // ---- epilogue: out-store for the last step (n = 127, buf = 1) ----
    bar_lgkm();
#pragma unroll
    for (int r = 0; r < 4; r++) {
        const int row = 4 * q + r;
        const float4 a = *(const float4*)&sRedC[row * 12];
        const float4 b = *(const float4*)&sRedC[row * 12 + 4];
        const float mu  = (a.x + a.y + a.z + a.w) * (1.0f / 64.0f);
        const float ex2 = (b.x + b.y + b.z + b.w) * (1.0f / 64.0f);
        const float rs  = rsqrtf(ex2 - mu * mu + EPS_);
        const float xqv = sXq32[1][row * 68 + col];
        xv_g[(NMINI - 1) * 1024 + row * 64 + col] =
            xqv + gamC * ((z2p[r] - mu) * rs) + betC;
    }
}

// ======================================================================
// post-norm: gather (B,NH,L,HD) -> LN over C=2048 -> fp16 hi/lo (B,L,C)
// (writes the pre-split A operand of the final GEMM directly)
// ======================================================================
__global__ __launch_bounds__(256)
void postln_kernel(const float* __restrict__ Ob, const float* __restrict__ pnw,
                   const float* __restrict__ pnb, _Float16* __restrict__ XNhi,
                   _Float16* __restrict__ XNlo)
{
    const int m = blockIdx.x;
    const int b = m >> 11, l = m & 2047;
    const int t = threadIdx.x;
    float v[8];
    float s1 = 0.0f, s2 = 0.0f;
    const int c0 = t * 8;
    const int hh = c0 >> 6, d0 = c0 & 63;
    const float* bas = Ob + (size_t)b * NHEADS * L_SEQ * HDIM + (size_t)l * HDIM
                     + (size_t)hh * (L_SEQ * HDIM) + d0;
    {
        const float4 va = *(const float4*)(bas);
        const float4 vb = *(const float4*)(bas + 4);
        v[0] = va.x; v[1] = va.y; v[2] = va.z; v[3] = va.w;
        v[4] = vb.x; v[5] = vb.y; v[6] = vb.z; v[7] = vb.w;
    }
#pragma unroll
    for (int j = 0; j < 8; j++) { s1 += v[j]; s2 += v[j] * v[j]; }
#pragma unroll
    for (int o = 1; o < 64; o <<= 1) { s1 += __shfl_xor(s1, o); s2 += __shfl_xor(s2, o); }
    __shared__ float r1[4], r2[4];
    const int w = t >> 6;
    if ((t & 63) == 0) { r1[w] = s1; r2[w] = s2; }
    __syncthreads();
    s1 = r1[0] + r1[1] + r1[2] + r1[3];
    s2 = r2[0] + r2[1] + r2[2] + r2[3];
    const float mu = s1 * (1.0f / 2048.0f);
    const float var = s2 * (1.0f / 2048.0f) - mu * mu;
    const float rstd = rsqrtf(var + EPS_);
    half8 oh, ol;
#pragma unroll
    for (int j = 0; j < 8; j++) {
        const float y = (v[j] - mu) * rstd * pnw[c0 + j] + pnb[c0 + j];
        const _Float16 hy = (_Float16)y;
        oh[j] = hy;
        ol[j] = (_Float16)(y - (float)hy);
    }
    *(half8*)(XNhi + (size_t)m * C_DIM + c0) = oh;
    *(half8*)(XNlo + (size_t)m * C_DIM + c0) = ol;
}

// ======================================================================
extern "C" void kernel_launch(void* const* d_in, const int* in_sizes, int n_in,
                              void* d_out, int out_size, void* d_ws, size_t ws_size,
                              hipStream_t stream)
{
    (void)in_sizes; (void)n_in; (void)out_size;
    const float* hidden  = (const float*)d_in[0];
    const float* Wq      = (const float*)d_in[2];
    const float* Wk      = (const float*)d_in[3];
    const float* Wv      = (const float*)d_in[4];
    const float* Wo      = (const float*)d_in[5];
    const float* W1      = (const float*)d_in[6];
    const float* b1      = (const float*)d_in[7];
    const float* wlr     = (const float*)d_in[8];
    const float* lr_bias = (const float*)d_in[9];
    const float* lt      = (const float*)d_in[10];
    const float* lnw     = (const float*)d_in[11];
    const float* lnb     = (const float*)d_in[12];
    const float* pnw     = (const float*)d_in[13];
    const float* pnb     = (const float*)d_in[14];

    const size_t TEN = (size_t)B_DIM * NHEADS * L_SEQ * HDIM;  // 16777216
    float* XQ  = (float*)d_ws;
    float* XK  = XQ + TEN;
    float* XVo = XK + TEN;
    float* LRS = XVo + TEN;                      // 262144 floats
    _Float16* Ahi = (_Float16*)(LRS + 262144);   // pre-split hidden (hi)
    _Float16* Alo = Ahi + TEN;                   // pre-split hidden (lo)
    _Float16* BThi = Alo + TEN;                  // fused QKV weight^T (hi)
    _Float16* BTlo = BThi + 3 * (size_t)C_DIM * C_DIM;
    _Float16* WThi = BTlo + 3 * (size_t)C_DIM * C_DIM;  // Wo^T (hi)
    _Float16* WTlo = WThi + (size_t)OUT_DIM * C_DIM;
    const size_t needBytes =
        (3 * TEN + 262144) * 4           // XQ/XK/XVo + LRS
        + TEN * 2 * 2                    // Ahi/Alo
        + 3 * (size_t)C_DIM * C_DIM * 4  // BThi/BTlo
        + (size_t)OUT_DIM * C_DIM * 4;   // WThi/WTlo
    const int fused = (ws_size >= needBytes) ? 1 : 0;
    const dim3 blk(256);

    if (fused) {
        // 6-launch path
        lr_kernel<<<dim3(B_DIM * L_SEQ), blk, 0, stream>>>(hidden, wlr, lr_bias,
                                                           LRS, Ahi, Alo);
        wtrans_all<<<dim3(13824), blk, 0, stream>>>(Wq, Wk, Wv, Wo,
                                                    BThi, BTlo, WThi, WTlo);
        gemm8<<<dim3(1536), dim3(512), 0, stream>>>(Ahi, Alo, BThi, BTlo,
                                                    XQ, 3 * C_DIM, 0, 1);
        scan_mfma<<<dim3(B_DIM * NHEADS), blk, 0, stream>>>(XQ, XK, XVo, LRS,
                                                            W1, b1, lt, lnw, lnb);
        _Float16* XNhi = (_Float16*)XQ;   // XQ dead after scan
        _Float16* XNlo = XNhi + TEN;
        postln_kernel<<<dim3(B_DIM * L_SEQ), blk, 0, stream>>>(XVo, pnw, pnb,
                                                               XNhi, XNlo);
        gemm8<<<dim3(192), dim3(512), 0, stream>>>(XNhi, XNlo, WThi, WTlo,
                                                   (float*)d_out, OUT_DIM, 1, 0);
    } else {
        // fallback: sequential per-matrix path, weight scratch in d_out
        _Float16* FBhi = (_Float16*)d_out;
        _Float16* FBlo = FBhi + (size_t)C_DIM * C_DIM;
        lr_kernel<<<dim3(B_DIM * L_SEQ), blk, 0, stream>>>(hidden, wlr, lr_bias,
                                                           LRS, nullptr, nullptr);
        const float* Wmats[3] = {Wq, Wk, Wv};
        float* outs[3] = {XQ, XK, XVo};
        for (int p = 0; p < 3; p++) {
            wtrans_kernel<<<dim3(64, 64), blk, 0, stream>>>(Wmats[p], FBhi, FBlo, C_DIM);
            gemm_f32<<<dim3(16, 64), blk, 0, stream>>>(hidden, FBhi, FBlo,
                                                       outs[p], 0, (p < 2) ? 1 : 0);
        }
        scan_mfma<<<dim3(B_DIM * NHEADS), blk, 0, stream>>>(XQ, XK, XVo, LRS,
                                                            W1, b1, lt, lnw, lnb);
        _Float16* XNhi = (_Float16*)XQ;
        _Float16* XNlo = XNhi + TEN;
        _Float16* FWhi = (_Float16*)XK;
        _Float16* FWlo = FWhi + (size_t)OUT_DIM * C_DIM;
        postln_kernel<<<dim3(B_DIM * L_SEQ), blk, 0, stream>>>(XVo, pnw, pnb,
                                                               XNhi, XNlo);
        wtrans_kernel<<<dim3(24, 64), blk, 0, stream>>>(Wo, FWhi, FWlo, OUT_DIM);
        gemm8<<<dim3(192), dim3(512), 0, stream>>>(XNhi, XNlo, FWhi, FWlo,
                                                   (float*)d_out, OUT_DIM, 1, 0);
    }
}